// Round 5
// baseline (140.405 us; speedup 1.0000x reference)
//
#include <hip/hip_runtime.h>
#include <hip/hip_fp16.h>
#include <math.h>

#define NN   256
#define LL   256
#define HH   512
#define MLPHv 2048
#define INCv 8
#define NCOLS 150   // 4 + 16 + 128 + 2 fused head columns

typedef _Float16 f16x8 __attribute__((ext_vector_type(8)));
typedef float    f32x4 __attribute__((ext_vector_type(4)));
typedef unsigned short ushort_t;

// ---------------------------------------------------------------------------
// fp32 -> fp16 hi/lo split:  a ≈ hi + lo/4096, |residual| <= 2^-22 |a|.
// ---------------------------------------------------------------------------
__device__ __forceinline__ void split1(float f, ushort_t& h, ushort_t& l)
{
    __half hh = __float2half_rn(f);
    h = __half_as_ushort(hh);
    l = __half_as_ushort(__float2half_rn((f - __half2float(hh)) * 4096.f));
}

__device__ __forceinline__ void pack8(const float* fv, uint4& hv, uint4& lv)
{
    ushort_t h[8], l[8];
#pragma unroll
    for (int j = 0; j < 8; ++j) split1(fv[j], h[j], l[j]);
    hv.x = (unsigned)h[0] | ((unsigned)h[1] << 16);
    hv.y = (unsigned)h[2] | ((unsigned)h[3] << 16);
    hv.z = (unsigned)h[4] | ((unsigned)h[5] << 16);
    hv.w = (unsigned)h[6] | ((unsigned)h[7] << 16);
    lv.x = (unsigned)l[0] | ((unsigned)l[1] << 16);
    lv.y = (unsigned)l[2] | ((unsigned)l[3] << 16);
    lv.z = (unsigned)l[4] | ((unsigned)l[5] << 16);
    lv.w = (unsigned)l[6] | ((unsigned)l[7] << 16);
}

// ---------------------------------------------------------------------------
// prep: bx<150 -> fused head weights (wave-shuffle reduce, 1 barrier);
//       bx>=150 -> z fp16 hi/lo split (32 blocks x 2048 elems).
// ---------------------------------------------------------------------------
__global__ __launch_bounds__(256) void prep_kernel(
    const float* __restrict__ z,
    const float* __restrict__ conv_w, const float* __restrict__ conv_b,
    const float* __restrict__ cw0, const float* __restrict__ cb0,
    const float* __restrict__ cw1, const float* __restrict__ cb1,
    const float* __restrict__ cw2, const float* __restrict__ cb2,
    const float* __restrict__ nw,  const float* __restrict__ nb,
    float* __restrict__ Mf, float* __restrict__ beta,
    ushort_t* __restrict__ zh, ushort_t* __restrict__ zl)
{
    const int bx  = blockIdx.x;
    const int tid = threadIdx.x;
    if (bx >= 150) {
        const int base = (bx - 150) * 2048 + tid * 8;
        float fv[8];
        float4 v0 = *(const float4*)&z[base];
        float4 v1 = *(const float4*)&z[base + 4];
        fv[0]=v0.x; fv[1]=v0.y; fv[2]=v0.z; fv[3]=v0.w;
        fv[4]=v1.x; fv[5]=v1.y; fv[6]=v1.z; fv[7]=v1.w;
        uint4 hv, lv;
        pack8(fv, hv, lv);
        *(uint4*)&zh[base] = hv;
        *(uint4*)&zl[base] = lv;
        return;
    }
    const int k = bx;
    const float* W; const float* B; int off, card;
    if (k < 4)        { W = cw0; B = cb0; off = 0;   card = 4;   }
    else if (k < 20)  { W = cw1; B = cb1; off = 4;   card = 16;  }
    else if (k < 148) { W = cw2; B = cb2; off = 20;  card = 128; }
    else              { W = nw;  B = nb;  off = 148; card = 2;   }
    const int kc = k - off;
    float part[INCv + 1];
#pragma unroll
    for (int c = 0; c <= INCv; ++c) part[c] = 0.f;
#pragma unroll
    for (int it = 0; it < 2; ++it) {
        const int h = tid + it * 256;
        const float wv = W[h * card + kc];
#pragma unroll
        for (int c = 0; c < INCv; ++c) part[c] += conv_w[h * INCv + c] * wv;
        part[INCv] += conv_b[h] * wv;
    }
    __shared__ float red[INCv + 1][4];
    const int lane = tid & 63, wave = tid >> 6;
#pragma unroll
    for (int c = 0; c <= INCv; ++c) {
        float v = part[c];
#pragma unroll
        for (int o = 32; o >= 1; o >>= 1) v += __shfl_down(v, o, 64);
        if (lane == 0) red[c][wave] = v;
    }
    __syncthreads();
    if (tid <= INCv) {
        const float s = red[tid][0] + red[tid][1] + red[tid][2] + red[tid][3];
        if (tid < INCv) Mf[tid * NCOLS + k] = s;
        else            beta[k] = s + B[kc];
    }
}

// ---------------------------------------------------------------------------
// fp16 hi/lo split MFMA GEMM emulating fp32 (24-bit effective):
//   acc = ah*bh + (ah*bl + al*bh)/4096
// A is PRE-SPLIT (Ah/Al fp16); W is fp32, split in-kernel.
// BM=BN=128, BK=64, 512 threads = 8 waves (2x4), 64x32 tile per wave.
// LDS fragment-direct layout: slot l = (row&15)+16*koct within 16-row group;
// frag read = ds_read_b128 at lane*16B, conflict-free.
// OUTMODE 0: fp32 partial at outp + blockIdx.z*524288
// OUTMODE 1: bias+relu then fp16 hi/lo split to outH/outL (direct, ksplit=1)
// ---------------------------------------------------------------------------
template <int OUTMODE>
__global__ __launch_bounds__(512, 2) void gemmhl(
    const ushort_t* __restrict__ Ah, const ushort_t* __restrict__ Al,
    const float* __restrict__ W, const float* __restrict__ bias,
    float* __restrict__ outp, ushort_t* __restrict__ outH, ushort_t* __restrict__ outL,
    int K, int kchunk, int nsteps)
{
    __shared__ ushort_t sAh[8192];
    __shared__ ushort_t sAl[8192];
    __shared__ ushort_t sBh[8192];
    __shared__ ushort_t sBl[8192];

    const int tid   = threadIdx.x;
    const int bn    = blockIdx.x * 128;
    const int bm    = blockIdx.y * 128;
    const int kbase = blockIdx.z * kchunk;
    const int lane  = tid & 63;
    const int wv    = tid >> 6, wr = wv >> 2, wc = wv & 3;
    const int rA    = tid >> 2, ktA = (tid & 3) << 4;   // A: row, 16-k strip
    const int nW    = tid & 127, kqW = tid >> 7;        // W: col, 16-k strip

    f32x4 accH[4][2], accC[4][2];
#pragma unroll
    for (int r = 0; r < 4; ++r)
#pragma unroll
        for (int c = 0; c < 2; ++c) {
            accH[r][c] = (f32x4){0.f, 0.f, 0.f, 0.f};
            accC[r][c] = (f32x4){0.f, 0.f, 0.f, 0.f};
        }

    uint4 aRegH[2], aRegL[2];
    float wReg[16];

    // ---- initial tile load (global -> regs) ----
    {
        const ushort_t* pH = Ah + (size_t)(bm + rA) * K + kbase + ktA;
        const ushort_t* pL = Al + (size_t)(bm + rA) * K + kbase + ktA;
        aRegH[0] = *(const uint4*)pH; aRegH[1] = *(const uint4*)(pH + 8);
        aRegL[0] = *(const uint4*)pL; aRegL[1] = *(const uint4*)(pL + 8);
#pragma unroll
        for (int j = 0; j < 16; ++j)
            wReg[j] = W[(size_t)(kbase + kqW * 16 + j) * 2048 + bn + nW];
    }

    for (int t = 0; t < nsteps; ++t) {
        // ---- write A tile (pre-split, no conversion) ----
#pragma unroll
        for (int o2 = 0; o2 < 2; ++o2) {
            const int oo   = ((tid & 3) << 1) + o2;      // k-octet 0..7
            const int base = ((oo >> 2) << 12) + ((rA >> 4) << 9)
                           + (((rA & 15) + ((oo & 3) << 4)) << 3);
            *(uint4*)&sAh[base] = aRegH[o2];
            *(uint4*)&sAl[base] = aRegL[o2];
        }
        // ---- convert + write W tile ----
#pragma unroll
        for (int o2 = 0; o2 < 2; ++o2) {
            uint4 hv, lv;
            pack8(&wReg[o2 * 8], hv, lv);
            const int oo   = (kqW << 1) + o2;
            const int base = ((oo >> 2) << 12) + ((nW >> 4) << 9)
                           + (((nW & 15) + ((oo & 3) << 4)) << 3);
            *(uint4*)&sBh[base] = hv;
            *(uint4*)&sBl[base] = lv;
        }

        // ---- prefetch tile t+1 into regs (overlaps MFMA below) ----
        if (t + 1 < nsteps) {
            const int kb = kbase + (t + 1) * 64;
            const ushort_t* pH = Ah + (size_t)(bm + rA) * K + kb + ktA;
            const ushort_t* pL = Al + (size_t)(bm + rA) * K + kb + ktA;
            aRegH[0] = *(const uint4*)pH; aRegH[1] = *(const uint4*)(pH + 8);
            aRegL[0] = *(const uint4*)pL; aRegL[1] = *(const uint4*)(pL + 8);
#pragma unroll
            for (int j = 0; j < 16; ++j)
                wReg[j] = W[(size_t)(kb + kqW * 16 + j) * 2048 + bn + nW];
        }

        __syncthreads();

        // ---- MFMA over the two K32 halves of this BK=64 tile ----
#pragma unroll
        for (int s = 0; s < 2; ++s) {
            f16x8 aH[4], aL[4], bH[2], bL[2];
#pragma unroll
            for (int r = 0; r < 4; ++r) {
                const int off = (s << 12) + (((wr << 2) + r) << 9) + (lane << 3);
                aH[r] = *(const f16x8*)&sAh[off];
                aL[r] = *(const f16x8*)&sAl[off];
            }
#pragma unroll
            for (int c = 0; c < 2; ++c) {
                const int off = (s << 12) + (((wc << 1) + c) << 9) + (lane << 3);
                bH[c] = *(const f16x8*)&sBh[off];
                bL[c] = *(const f16x8*)&sBl[off];
            }
#pragma unroll
            for (int r = 0; r < 4; ++r)
#pragma unroll
                for (int c = 0; c < 2; ++c) {
                    accH[r][c] = __builtin_amdgcn_mfma_f32_16x16x32_f16(aH[r], bH[c], accH[r][c], 0, 0, 0);
                    accC[r][c] = __builtin_amdgcn_mfma_f32_16x16x32_f16(aH[r], bL[c], accC[r][c], 0, 0, 0);
                    accC[r][c] = __builtin_amdgcn_mfma_f32_16x16x32_f16(aL[r], bH[c], accC[r][c], 0, 0, 0);
                }
        }
        __syncthreads();
    }

    // ---- epilogue ----
    const float inv = 1.f / 4096.f;
#pragma unroll
    for (int r = 0; r < 4; ++r)
#pragma unroll
        for (int c = 0; c < 2; ++c) {
            const int row = bm + wr * 64 + r * 16 + ((lane >> 4) << 2);
            const int col = bn + wc * 32 + c * 16 + (lane & 15);
#pragma unroll
            for (int e = 0; e < 4; ++e) {
                float v = accH[r][c][e] + accC[r][c][e] * inv;
                if (OUTMODE == 1) {
                    v = fmaxf(v + bias[col], 0.f);
                    ushort_t h, l;
                    split1(v, h, l);
                    outH[(size_t)(row + e) * 2048 + col] = h;
                    outL[(size_t)(row + e) * 2048 + col] = l;
                } else {
                    (outp + (size_t)blockIdx.z * 524288)[(size_t)(row + e) * 2048 + col] = v;
                }
            }
        }
}

// ---------------------------------------------------------------------------
// Reduce 8 partials + bias + relu. SPLITOUT: emit fp16 hi/lo (next layer's
// A operand); else emit fp32 (rh2 for heads).
// ---------------------------------------------------------------------------
template <bool SPLITOUT>
__global__ __launch_bounds__(256) void reduce_k(
    const float* __restrict__ part, const float* __restrict__ bias,
    float* __restrict__ outF, ushort_t* __restrict__ outH, ushort_t* __restrict__ outL)
{
    const int r  = blockIdx.x;        // 512 blocks
    const int ct = r & 15, rg = r >> 4;
    const int e  = threadIdx.x * 4;
    const int row = rg * 8 + (e >> 7);
    const int col = ct * 128 + (e & 127);
    const size_t idx = (size_t)row * 2048 + col;
    float4 s = *(const float4*)&bias[col];
#pragma unroll
    for (int k = 0; k < 8; ++k) {
        const float4 p = *(const float4*)&part[(size_t)k * 524288 + idx];
        s.x += p.x; s.y += p.y; s.z += p.z; s.w += p.w;
    }
    s.x = fmaxf(s.x, 0.f); s.y = fmaxf(s.y, 0.f);
    s.z = fmaxf(s.z, 0.f); s.w = fmaxf(s.w, 0.f);
    if (SPLITOUT) {
        ushort_t h[4], l[4];
        split1(s.x, h[0], l[0]); split1(s.y, h[1], l[1]);
        split1(s.z, h[2], l[2]); split1(s.w, h[3], l[3]);
        ushort4 hv = {h[0], h[1], h[2], h[3]};
        ushort4 lv = {l[0], l[1], l[2], l[3]};
        *(ushort4*)&outH[idx] = hv;
        *(ushort4*)&outL[idx] = lv;
    } else {
        *(float4*)&outF[idx] = s;
    }
}

// ---------------------------------------------------------------------------
// Heads: bx<96 -> cat (g = bx>>5), bx>=96 -> num.
// ---------------------------------------------------------------------------
__global__ __launch_bounds__(256) void heads_kernel(
    const float* __restrict__ rh, const float* __restrict__ Mf,
    const float* __restrict__ beta, const int* __restrict__ cat_target,
    const float* __restrict__ num_target, float* __restrict__ out)
{
    const int bx  = blockIdx.x;
    const int tid = threadIdx.x;
    __shared__ float Ms[INCv][128];
    __shared__ float Bsh[128];
    if (bx < 96) {
        const int g = bx >> 5;
        const int card = (g == 0) ? 4 : (g == 1) ? 16 : 128;
        const int off  = (g == 0) ? 0 : (g == 1) ? 4  : 20;
        for (int i = tid; i < card * INCv; i += 256) {
            int c = i / card, k = i % card;
            Ms[c][k] = Mf[c * NCOLS + off + k];
        }
        for (int i = tid; i < card; i += 256) Bsh[i] = beta[off + i];
        __syncthreads();

        const int idx = (bx & 31) * 256 + tid;
        const int n = idx >> 5, j = idx & 31;
        const int ci = g * 32 + j;
        const int l  = ci * 2;
        float rv[INCv];
#pragma unroll
        for (int c = 0; c < INCv; ++c) rv[c] = rh[n * MLPHv + c * LL + l];

        float mx = -1e30f; int arg = 0;
        for (int k = 0; k < card; ++k) {
            float s = Bsh[k];
#pragma unroll
            for (int c = 0; c < INCv; ++c) s += rv[c] * Ms[c][k];
            if (s > mx) { mx = s; arg = k; }
        }
        const int tg = cat_target[n * 96 + ci];
        float sum = 0.f, stg = 0.f;
        for (int k = 0; k < card; ++k) {
            float s = Bsh[k];
#pragma unroll
            for (int c = 0; c < INCv; ++c) s += rv[c] * Ms[c][k];
            sum += expf(s - mx);
            if (k == tg) stg = s;
        }
        float lse = mx + logf(sum);
        out[NN * LL * 3 + n * 96 + ci] = lse - stg;
        float* u = out + (size_t)(n * LL + l) * 3;
        u[0] = (float)arg; u[1] = 0.f; u[2] = 0.f;
    } else {
        const int idx = (bx - 96) * 256 + tid;  // 0..40959
        const int n = idx / 160, ni = idx % 160;
        const int l = (ni < 96) ? (2 * ni + 1) : (96 + ni);
        float rv[INCv];
#pragma unroll
        for (int c = 0; c < INCv; ++c) rv[c] = rh[n * MLPHv + c * LL + l];
        float p0 = beta[148], p1 = beta[149];
#pragma unroll
        for (int c = 0; c < INCv; ++c) {
            p0 += rv[c] * Mf[c * NCOLS + 148];
            p1 += rv[c] * Mf[c * NCOLS + 149];
        }
        float mu = 1.f / (1.f + expf(-p0));
        float sp = (p1 > 20.f) ? p1 : log1pf(expf(p1));
        float s  = sp + 1e-4f;
        const float hb = 1.f / 198.f;
        float t  = num_target[n * 160 + ni];
        float cp = 1.f / (1.f + expf(-((t + hb - mu) / s)));
        float cm = 1.f / (1.f + expf(-((t - hb - mu) / s)));
        float prob = (t < hb) ? cp : ((t > 1.f - hb) ? (1.f - cm) : (cp - cm));
        out[NN * LL * 3 + NN * 96 + n * 160 + ni] = -logf(fmaxf(prob, 1e-7f));
        float* u = out + (size_t)(n * LL + l) * 3;
        u[0] = 0.f; u[1] = rintf(mu * 99.f) / 99.f; u[2] = 0.f;
    }
}

// ---------------------------------------------------------------------------
extern "C" void kernel_launch(void* const* d_in, const int* in_sizes, int n_in,
                              void* d_out, int out_size, void* d_ws, size_t ws_size,
                              hipStream_t stream)
{
    const float* z   = (const float*)d_in[0];
    const float* w0  = (const float*)d_in[1];
    const float* b0  = (const float*)d_in[2];
    const float* w1  = (const float*)d_in[3];
    const float* b1  = (const float*)d_in[4];
    const float* w2  = (const float*)d_in[5];
    const float* b2  = (const float*)d_in[6];
    const float* cvw = (const float*)d_in[7];
    const float* cvb = (const float*)d_in[8];
    const float* cw0 = (const float*)d_in[9];
    const float* cb0 = (const float*)d_in[10];
    const float* cw1 = (const float*)d_in[11];
    const float* cb1 = (const float*)d_in[12];
    const float* cw2 = (const float*)d_in[13];
    const float* cb2 = (const float*)d_in[14];
    const float* nw  = (const float*)d_in[15];
    const float* nb  = (const float*)d_in[16];
    const float* num_target = (const float*)d_in[17];
    const int*   cat_target = (const int*)d_in[18];
    float* out = (float*)d_out;
    float* ws  = (float*)d_ws;

    size_t o = 0;
    float*    part = ws;                       o += 8ull * 524288;   // 16 MB
    float*    rh2  = ws + o;                   o += 524288;
    float*    Mf   = ws + o;                   o += 1536;
    float*    beta = ws + o;                   o += 256;
    ushort_t* zh   = (ushort_t*)(ws + o);      o += 32768;           // 256x256 fp16
    ushort_t* zl   = (ushort_t*)(ws + o);      o += 32768;
    ushort_t* r0h  = (ushort_t*)(ws + o);      o += 262144;          // 256x2048 fp16
    ushort_t* r0l  = (ushort_t*)(ws + o);      o += 262144;
    ushort_t* r1h  = (ushort_t*)(ws + o);      o += 262144;
    ushort_t* r1l  = (ushort_t*)(ws + o);      o += 262144;

    // 1. prep: fused head weights + z hi/lo split
    prep_kernel<<<dim3(182), 256, 0, stream>>>(
        z, cvw, cvb, cw0, cb0, cw1, cb1, cw2, cb2, nw, nb, Mf, beta, zh, zl);

    // 2. layer 0 (K=256) direct: rh0 = relu(z@w0+b0) -> fp16 hi/lo
    gemmhl<1><<<dim3(16, 2, 1), 512, 0, stream>>>(
        zh, zl, w0, b0, nullptr, r0h, r0l, 256, 256, 4);

    // 3-4. layer 1 (K=2048), split-K=8 + reduce -> fp16 hi/lo
    gemmhl<0><<<dim3(16, 2, 8), 512, 0, stream>>>(
        r0h, r0l, w1, nullptr, part, nullptr, nullptr, 2048, 256, 4);
    reduce_k<true><<<dim3(512), 256, 0, stream>>>(part, b1, nullptr, r1h, r1l);

    // 5-6. layer 2 (K=2048), split-K=8 + reduce -> fp32 rh2
    gemmhl<0><<<dim3(16, 2, 8), 512, 0, stream>>>(
        r1h, r1l, w2, nullptr, part, nullptr, nullptr, 2048, 256, 4);
    reduce_k<false><<<dim3(512), 256, 0, stream>>>(part, b2, rh2, nullptr, nullptr);

    // 7. heads
    heads_kernel<<<dim3(256), 256, 0, stream>>>(
        rh2, Mf, beta, cat_target, num_target, out);
}

// Round 6
// 118.159 us; speedup vs baseline: 1.1883x; 1.1883x over previous
//
#include <hip/hip_runtime.h>
#include <hip/hip_fp16.h>
#include <math.h>

#define NN   256
#define LL   256
#define HH   512
#define MLPHv 2048
#define INCv 8
#define NCOLS 150   // 4 + 16 + 128 + 2 fused head columns

typedef _Float16 f16x8 __attribute__((ext_vector_type(8)));
typedef float    f32x4 __attribute__((ext_vector_type(4)));
typedef unsigned short ushort_t;

// ---------------------------------------------------------------------------
// fp32 -> fp16 hi/lo split:  a ≈ hi + lo/4096, |residual| <= 2^-22 |a|.
// ---------------------------------------------------------------------------
__device__ __forceinline__ void split1(float f, ushort_t& h, ushort_t& l)
{
    __half hh = __float2half_rn(f);
    h = __half_as_ushort(hh);
    l = __half_as_ushort(__float2half_rn((f - __half2float(hh)) * 4096.f));
}

__device__ __forceinline__ void pack8(const float* fv, uint4& hv, uint4& lv)
{
    ushort_t h[8], l[8];
#pragma unroll
    for (int j = 0; j < 8; ++j) split1(fv[j], h[j], l[j]);
    hv.x = (unsigned)h[0] | ((unsigned)h[1] << 16);
    hv.y = (unsigned)h[2] | ((unsigned)h[3] << 16);
    hv.z = (unsigned)h[4] | ((unsigned)h[5] << 16);
    hv.w = (unsigned)h[6] | ((unsigned)h[7] << 16);
    lv.x = (unsigned)l[0] | ((unsigned)l[1] << 16);
    lv.y = (unsigned)l[2] | ((unsigned)l[3] << 16);
    lv.z = (unsigned)l[4] | ((unsigned)l[5] << 16);
    lv.w = (unsigned)l[6] | ((unsigned)l[7] << 16);
}

// ---------------------------------------------------------------------------
// wsplit: transpose + hi/lo split weights into Wt[col][k] fp16 pairs.
// 64x64 tiles. bid<1024: w1; <2048: w2; else w0 (128 tiles, K=256).
// Phase A: coalesced row reads -> split -> LDS[k][c] (row-contig writes).
// Phase B: per-col gather from LDS (padded stride 65) -> 32-B contig
// writes per lane, 4 lanes = 128 B per output col-row.
// ---------------------------------------------------------------------------
__global__ __launch_bounds__(256) void wsplit_kernel(
    const float* __restrict__ w0, const float* __restrict__ w1,
    const float* __restrict__ w2,
    ushort_t* __restrict__ W0th, ushort_t* __restrict__ W0tl,
    ushort_t* __restrict__ W1th, ushort_t* __restrict__ W1tl,
    ushort_t* __restrict__ W2th, ushort_t* __restrict__ W2tl)
{
    __shared__ ushort_t lh[64 * 65];
    __shared__ ushort_t ll[64 * 65];
    const int bid = blockIdx.x;
    const int tid = threadIdx.x;
    const float* src; ushort_t* dh; ushort_t* dl; int K, t;
    if (bid < 1024)      { src = w1; dh = W1th; dl = W1tl; K = 2048; t = bid; }
    else if (bid < 2048) { src = w2; dh = W2th; dl = W2tl; K = 2048; t = bid - 1024; }
    else                 { src = w0; dh = W0th; dl = W0tl; K = 256;  t = bid - 2048; }
    const int k0 = (t >> 5) * 64;
    const int n0 = (t & 31) * 64;

    // Phase A: read 64(k) x 64(n) fp32 tile, split, store LDS [k][n]
    {
        const int r  = tid >> 2;            // k-row 0..63
        const int cb = (tid & 3) * 16;      // col base
        const float* p = src + (size_t)(k0 + r) * 2048 + n0 + cb;
        float fv[16];
#pragma unroll
        for (int q = 0; q < 4; ++q) {
            float4 v = *(const float4*)(p + q * 4);
            fv[q * 4 + 0] = v.x; fv[q * 4 + 1] = v.y;
            fv[q * 4 + 2] = v.z; fv[q * 4 + 3] = v.w;
        }
#pragma unroll
        for (int j = 0; j < 16; ++j) {
            ushort_t h, l;
            split1(fv[j], h, l);
            lh[r * 65 + cb + j] = h;
            ll[r * 65 + cb + j] = l;
        }
    }
    __syncthreads();

    // Phase B: per-col gather 16 k, pack, write Wt[col][k]
    {
        const int c   = tid >> 2;           // col 0..63
        const int kb2 = (tid & 3) * 16;     // k base
        ushort_t hb[16], lb[16];
#pragma unroll
        for (int j = 0; j < 16; ++j) {
            hb[j] = lh[(kb2 + j) * 65 + c];
            lb[j] = ll[(kb2 + j) * 65 + c];
        }
        uint4 v0, v1;
        v0.x = (unsigned)hb[0]  | ((unsigned)hb[1]  << 16);
        v0.y = (unsigned)hb[2]  | ((unsigned)hb[3]  << 16);
        v0.z = (unsigned)hb[4]  | ((unsigned)hb[5]  << 16);
        v0.w = (unsigned)hb[6]  | ((unsigned)hb[7]  << 16);
        v1.x = (unsigned)hb[8]  | ((unsigned)hb[9]  << 16);
        v1.y = (unsigned)hb[10] | ((unsigned)hb[11] << 16);
        v1.z = (unsigned)hb[12] | ((unsigned)hb[13] << 16);
        v1.w = (unsigned)hb[14] | ((unsigned)hb[15] << 16);
        ushort_t* po = dh + (size_t)(n0 + c) * K + k0 + kb2;
        *(uint4*)po = v0;
        *(uint4*)(po + 8) = v1;
        v0.x = (unsigned)lb[0]  | ((unsigned)lb[1]  << 16);
        v0.y = (unsigned)lb[2]  | ((unsigned)lb[3]  << 16);
        v0.z = (unsigned)lb[4]  | ((unsigned)lb[5]  << 16);
        v0.w = (unsigned)lb[6]  | ((unsigned)lb[7]  << 16);
        v1.x = (unsigned)lb[8]  | ((unsigned)lb[9]  << 16);
        v1.y = (unsigned)lb[10] | ((unsigned)lb[11] << 16);
        v1.z = (unsigned)lb[12] | ((unsigned)lb[13] << 16);
        v1.w = (unsigned)lb[14] | ((unsigned)lb[15] << 16);
        po = dl + (size_t)(n0 + c) * K + k0 + kb2;
        *(uint4*)po = v0;
        *(uint4*)(po + 8) = v1;
    }
}

// ---------------------------------------------------------------------------
// prep: bx<150 -> fused head weights (wave-shuffle reduce, 1 barrier);
//       bx>=150 -> z fp16 hi/lo split (32 blocks x 2048 elems).
// ---------------------------------------------------------------------------
__global__ __launch_bounds__(256) void prep_kernel(
    const float* __restrict__ z,
    const float* __restrict__ conv_w, const float* __restrict__ conv_b,
    const float* __restrict__ cw0, const float* __restrict__ cb0,
    const float* __restrict__ cw1, const float* __restrict__ cb1,
    const float* __restrict__ cw2, const float* __restrict__ cb2,
    const float* __restrict__ nw,  const float* __restrict__ nb,
    float* __restrict__ Mf, float* __restrict__ beta,
    ushort_t* __restrict__ zh, ushort_t* __restrict__ zl)
{
    const int bx  = blockIdx.x;
    const int tid = threadIdx.x;
    if (bx >= 150) {
        const int base = (bx - 150) * 2048 + tid * 8;
        float fv[8];
        float4 v0 = *(const float4*)&z[base];
        float4 v1 = *(const float4*)&z[base + 4];
        fv[0]=v0.x; fv[1]=v0.y; fv[2]=v0.z; fv[3]=v0.w;
        fv[4]=v1.x; fv[5]=v1.y; fv[6]=v1.z; fv[7]=v1.w;
        uint4 hv, lv;
        pack8(fv, hv, lv);
        *(uint4*)&zh[base] = hv;
        *(uint4*)&zl[base] = lv;
        return;
    }
    const int k = bx;
    const float* W; const float* B; int off, card;
    if (k < 4)        { W = cw0; B = cb0; off = 0;   card = 4;   }
    else if (k < 20)  { W = cw1; B = cb1; off = 4;   card = 16;  }
    else if (k < 148) { W = cw2; B = cb2; off = 20;  card = 128; }
    else              { W = nw;  B = nb;  off = 148; card = 2;   }
    const int kc = k - off;
    float part[INCv + 1];
#pragma unroll
    for (int c = 0; c <= INCv; ++c) part[c] = 0.f;
#pragma unroll
    for (int it = 0; it < 2; ++it) {
        const int h = tid + it * 256;
        const float wv = W[h * card + kc];
#pragma unroll
        for (int c = 0; c < INCv; ++c) part[c] += conv_w[h * INCv + c] * wv;
        part[INCv] += conv_b[h] * wv;
    }
    __shared__ float red[INCv + 1][4];
    const int lane = tid & 63, wave = tid >> 6;
#pragma unroll
    for (int c = 0; c <= INCv; ++c) {
        float v = part[c];
#pragma unroll
        for (int o = 32; o >= 1; o >>= 1) v += __shfl_down(v, o, 64);
        if (lane == 0) red[c][wave] = v;
    }
    __syncthreads();
    if (tid <= INCv) {
        const float s = red[tid][0] + red[tid][1] + red[tid][2] + red[tid][3];
        if (tid < INCv) Mf[tid * NCOLS + k] = s;
        else            beta[k] = s + B[kc];
    }
}

// ---------------------------------------------------------------------------
// No-LDS, no-barrier fp16 hi/lo MFMA GEMM. All operands fragment-loaded
// directly from global (A [M][K], Bt [N][K], both fp16 hi/lo pairs, 16-B
// contiguous per lane). 512 thr = 8 waves (2 wr x 4 wc), 64x32 per wave.
// acc = ah*bh + (ah*bl + al*bh)/4096. Ping-pong reg pipeline over K32
// steps (steps must be even). Writes fp32 partial at part + bz*524288.
// ---------------------------------------------------------------------------
#define LOADSET(AH, AL, BH, BL, DISP)                                   \
    do {                                                                \
        _Pragma("unroll")                                               \
        for (int r = 0; r < 4; ++r) {                                   \
            AH[r] = *(const f16x8*)(pAh[r] + (DISP));                   \
            AL[r] = *(const f16x8*)(pAl[r] + (DISP));                   \
        }                                                               \
        _Pragma("unroll")                                               \
        for (int c = 0; c < 2; ++c) {                                   \
            BH[c] = *(const f16x8*)(pBh[c] + (DISP));                   \
            BL[c] = *(const f16x8*)(pBl[c] + (DISP));                   \
        }                                                               \
    } while (0)

#define MFMASET(AH, AL, BH, BL)                                                          \
    do {                                                                                 \
        _Pragma("unroll")                                                                \
        for (int r = 0; r < 4; ++r) {                                                    \
            _Pragma("unroll")                                                            \
            for (int c = 0; c < 2; ++c) {                                                \
                accH[r][c] = __builtin_amdgcn_mfma_f32_16x16x32_f16(AH[r], BH[c], accH[r][c], 0, 0, 0); \
                accC[r][c] = __builtin_amdgcn_mfma_f32_16x16x32_f16(AH[r], BL[c], accC[r][c], 0, 0, 0); \
                accC[r][c] = __builtin_amdgcn_mfma_f32_16x16x32_f16(AL[r], BH[c], accC[r][c], 0, 0, 0); \
            }                                                                            \
        }                                                                                \
    } while (0)

__global__ __launch_bounds__(512) void gemm_direct(
    const ushort_t* __restrict__ Ah, const ushort_t* __restrict__ Al,
    const ushort_t* __restrict__ Bth, const ushort_t* __restrict__ Btl,
    float* __restrict__ part, int K, int kchunk)
{
    const int tid   = threadIdx.x;
    const int bn    = blockIdx.x * 128;
    const int bm    = blockIdx.y * 128;
    const int kbase = blockIdx.z * kchunk;
    const int steps = kchunk >> 5;          // K32 steps, even
    const int lane  = tid & 63;
    const int wv    = tid >> 6, wr = wv >> 2, wc = wv & 3;
    const int koff  = kbase + ((lane >> 4) << 3);

    const ushort_t* pAh[4]; const ushort_t* pAl[4];
    const ushort_t* pBh[2]; const ushort_t* pBl[2];
#pragma unroll
    for (int r = 0; r < 4; ++r) {
        const size_t o = (size_t)(bm + wr * 64 + r * 16 + (lane & 15)) * K + koff;
        pAh[r] = Ah + o; pAl[r] = Al + o;
    }
#pragma unroll
    for (int c = 0; c < 2; ++c) {
        const size_t o = (size_t)(bn + wc * 32 + c * 16 + (lane & 15)) * K + koff;
        pBh[c] = Bth + o; pBl[c] = Btl + o;
    }

    f32x4 accH[4][2], accC[4][2];
#pragma unroll
    for (int r = 0; r < 4; ++r)
#pragma unroll
        for (int c = 0; c < 2; ++c) {
            accH[r][c] = (f32x4){0.f, 0.f, 0.f, 0.f};
            accC[r][c] = (f32x4){0.f, 0.f, 0.f, 0.f};
        }

    f16x8 aH0[4], aL0[4], bH0[2], bL0[2];
    f16x8 aH1[4], aL1[4], bH1[2], bL1[2];

    int disp = 0;
    LOADSET(aH0, aL0, bH0, bL0, 0);
    for (int s = 0; s < steps; s += 2) {
        LOADSET(aH1, aL1, bH1, bL1, disp + 32);
        MFMASET(aH0, aL0, bH0, bL0);
        if (s + 2 < steps) LOADSET(aH0, aL0, bH0, bL0, disp + 64);
        MFMASET(aH1, aL1, bH1, bL1);
        disp += 64;
    }

    // epilogue: fp32 partial
    const float inv = 1.f / 4096.f;
    float* pout = part + (size_t)blockIdx.z * 524288;
#pragma unroll
    for (int r = 0; r < 4; ++r)
#pragma unroll
        for (int c = 0; c < 2; ++c) {
            const int row = bm + wr * 64 + r * 16 + ((lane >> 4) << 2);
            const int col = bn + wc * 32 + c * 16 + (lane & 15);
#pragma unroll
            for (int e = 0; e < 4; ++e)
                pout[(size_t)(row + e) * 2048 + col] = accH[r][c][e] + accC[r][c][e] * inv;
        }
}

// ---------------------------------------------------------------------------
// Reduce KS partials + bias + relu. SPLITOUT: emit fp16 hi/lo pairs;
// else fp32.
// ---------------------------------------------------------------------------
template <bool SPLITOUT>
__global__ __launch_bounds__(256) void reduce_k(
    const float* __restrict__ part, const float* __restrict__ bias,
    float* __restrict__ outF, ushort_t* __restrict__ outH, ushort_t* __restrict__ outL,
    int KS)
{
    const int r  = blockIdx.x;        // 512 blocks
    const int ct = r & 15, rg = r >> 4;
    const int e  = threadIdx.x * 4;
    const int row = rg * 8 + (e >> 7);
    const int col = ct * 128 + (e & 127);
    const size_t idx = (size_t)row * 2048 + col;
    float4 s = *(const float4*)&bias[col];
    for (int k = 0; k < KS; ++k) {
        const float4 p = *(const float4*)&part[(size_t)k * 524288 + idx];
        s.x += p.x; s.y += p.y; s.z += p.z; s.w += p.w;
    }
    s.x = fmaxf(s.x, 0.f); s.y = fmaxf(s.y, 0.f);
    s.z = fmaxf(s.z, 0.f); s.w = fmaxf(s.w, 0.f);
    if (SPLITOUT) {
        ushort_t h[4], l[4];
        split1(s.x, h[0], l[0]); split1(s.y, h[1], l[1]);
        split1(s.z, h[2], l[2]); split1(s.w, h[3], l[3]);
        ushort4 hv = {h[0], h[1], h[2], h[3]};
        ushort4 lv = {l[0], l[1], l[2], l[3]};
        *(ushort4*)&outH[idx] = hv;
        *(ushort4*)&outL[idx] = lv;
    } else {
        *(float4*)&outF[idx] = s;
    }
}

// ---------------------------------------------------------------------------
// Heads: bx<96 -> cat (g = bx>>5), bx>=96 -> num.
// ---------------------------------------------------------------------------
__global__ __launch_bounds__(256) void heads_kernel(
    const float* __restrict__ rh, const float* __restrict__ Mf,
    const float* __restrict__ beta, const int* __restrict__ cat_target,
    const float* __restrict__ num_target, float* __restrict__ out)
{
    const int bx  = blockIdx.x;
    const int tid = threadIdx.x;
    __shared__ float Ms[INCv][128];
    __shared__ float Bsh[128];
    if (bx < 96) {
        const int g = bx >> 5;
        const int card = (g == 0) ? 4 : (g == 1) ? 16 : 128;
        const int off  = (g == 0) ? 0 : (g == 1) ? 4  : 20;
        for (int i = tid; i < card * INCv; i += 256) {
            int c = i / card, k = i % card;
            Ms[c][k] = Mf[c * NCOLS + off + k];
        }
        for (int i = tid; i < card; i += 256) Bsh[i] = beta[off + i];
        __syncthreads();

        const int idx = (bx & 31) * 256 + tid;
        const int n = idx >> 5, j = idx & 31;
        const int ci = g * 32 + j;
        const int l  = ci * 2;
        float rv[INCv];
#pragma unroll
        for (int c = 0; c < INCv; ++c) rv[c] = rh[n * MLPHv + c * LL + l];

        float mx = -1e30f; int arg = 0;
        for (int k = 0; k < card; ++k) {
            float s = Bsh[k];
#pragma unroll
            for (int c = 0; c < INCv; ++c) s += rv[c] * Ms[c][k];
            if (s > mx) { mx = s; arg = k; }
        }
        const int tg = cat_target[n * 96 + ci];
        float sum = 0.f, stg = 0.f;
        for (int k = 0; k < card; ++k) {
            float s = Bsh[k];
#pragma unroll
            for (int c = 0; c < INCv; ++c) s += rv[c] * Ms[c][k];
            sum += expf(s - mx);
            if (k == tg) stg = s;
        }
        float lse = mx + logf(sum);
        out[NN * LL * 3 + n * 96 + ci] = lse - stg;
        float* u = out + (size_t)(n * LL + l) * 3;
        u[0] = (float)arg; u[1] = 0.f; u[2] = 0.f;
    } else {
        const int idx = (bx - 96) * 256 + tid;  // 0..40959
        const int n = idx / 160, ni = idx % 160;
        const int l = (ni < 96) ? (2 * ni + 1) : (96 + ni);
        float rv[INCv];
#pragma unroll
        for (int c = 0; c < INCv; ++c) rv[c] = rh[n * MLPHv + c * LL + l];
        float p0 = beta[148], p1 = beta[149];
#pragma unroll
        for (int c = 0; c < INCv; ++c) {
            p0 += rv[c] * Mf[c * NCOLS + 148];
            p1 += rv[c] * Mf[c * NCOLS + 149];
        }
        float mu = 1.f / (1.f + expf(-p0));
        float sp = (p1 > 20.f) ? p1 : log1pf(expf(p1));
        float s  = sp + 1e-4f;
        const float hb = 1.f / 198.f;
        float t  = num_target[n * 160 + ni];
        float cp = 1.f / (1.f + expf(-((t + hb - mu) / s)));
        float cm = 1.f / (1.f + expf(-((t - hb - mu) / s)));
        float prob = (t < hb) ? cp : ((t > 1.f - hb) ? (1.f - cm) : (cp - cm));
        out[NN * LL * 3 + NN * 96 + n * 160 + ni] = -logf(fmaxf(prob, 1e-7f));
        float* u = out + (size_t)(n * LL + l) * 3;
        u[0] = 0.f; u[1] = rintf(mu * 99.f) / 99.f; u[2] = 0.f;
    }
}

// ---------------------------------------------------------------------------
extern "C" void kernel_launch(void* const* d_in, const int* in_sizes, int n_in,
                              void* d_out, int out_size, void* d_ws, size_t ws_size,
                              hipStream_t stream)
{
    const float* z   = (const float*)d_in[0];
    const float* w0  = (const float*)d_in[1];
    const float* b0  = (const float*)d_in[2];
    const float* w1  = (const float*)d_in[3];
    const float* b1  = (const float*)d_in[4];
    const float* w2  = (const float*)d_in[5];
    const float* b2  = (const float*)d_in[6];
    const float* cvw = (const float*)d_in[7];
    const float* cvb = (const float*)d_in[8];
    const float* cw0 = (const float*)d_in[9];
    const float* cb0 = (const float*)d_in[10];
    const float* cw1 = (const float*)d_in[11];
    const float* cb1 = (const float*)d_in[12];
    const float* cw2 = (const float*)d_in[13];
    const float* cb2 = (const float*)d_in[14];
    const float* nw  = (const float*)d_in[15];
    const float* nb  = (const float*)d_in[16];
    const float* num_target = (const float*)d_in[17];
    const int*   cat_target = (const int*)d_in[18];
    float* out = (float*)d_out;
    float* ws  = (float*)d_ws;

    size_t o = 0;
    float*    part = ws;                    o += 8ull * 524288;   // 16 MB
    float*    rh2  = ws + o;                o += 524288;
    float*    Mf   = ws + o;                o += 1536;
    float*    beta = ws + o;                o += 256;
    ushort_t* zh   = (ushort_t*)(ws + o);   o += 32768;           // 256x256
    ushort_t* zl   = (ushort_t*)(ws + o);   o += 32768;
    ushort_t* r0h  = (ushort_t*)(ws + o);   o += 262144;          // 256x2048
    ushort_t* r0l  = (ushort_t*)(ws + o);   o += 262144;
    ushort_t* r1h  = (ushort_t*)(ws + o);   o += 262144;
    ushort_t* r1l  = (ushort_t*)(ws + o);   o += 262144;
    ushort_t* W0th = (ushort_t*)(ws + o);   o += 262144;          // 2048x256
    ushort_t* W0tl = (ushort_t*)(ws + o);   o += 262144;
    ushort_t* W1th = (ushort_t*)(ws + o);   o += 2097152;         // 2048x2048
    ushort_t* W1tl = (ushort_t*)(ws + o);   o += 2097152;
    ushort_t* W2th = (ushort_t*)(ws + o);   o += 2097152;
    ushort_t* W2tl = (ushort_t*)(ws + o);   o += 2097152;

    // 1. transpose + split all weights into Wt[col][k] fp16 pairs
    wsplit_kernel<<<dim3(2176), 256, 0, stream>>>(
        w0, w1, w2, W0th, W0tl, W1th, W1tl, W2th, W2tl);

    // 2. head-weight fusion + z split
    prep_kernel<<<dim3(182), 256, 0, stream>>>(
        z, cvw, cvb, cw0, cb0, cw1, cb1, cw2, cb2, nw, nb, Mf, beta, zh, zl);

    // 3-4. layer 0 (K=256, ksplit=4, steps=2) + reduce -> fp16 pairs
    gemm_direct<<<dim3(16, 2, 4), 512, 0, stream>>>(
        zh, zl, W0th, W0tl, part, 256, 64);
    reduce_k<true><<<dim3(512), 256, 0, stream>>>(part, b0, nullptr, r0h, r0l, 4);

    // 5-6. layer 1 (K=2048, ksplit=8, steps=8) + reduce -> fp16 pairs
    gemm_direct<<<dim3(16, 2, 8), 512, 0, stream>>>(
        r0h, r0l, W1th, W1tl, part, 2048, 256);
    reduce_k<true><<<dim3(512), 256, 0, stream>>>(part, b1, nullptr, r1h, r1l, 8);

    // 7-8. layer 2 (K=2048, ksplit=8, steps=8) + reduce -> fp32 rh2
    gemm_direct<<<dim3(16, 2, 8), 512, 0, stream>>>(
        r1h, r1l, W2th, W2tl, part, 2048, 256);
    reduce_k<false><<<dim3(512), 256, 0, stream>>>(part, b2, rh2, nullptr, nullptr, 8);

    // 9. heads
    heads_kernel<<<dim3(256), 256, 0, stream>>>(
        rh2, Mf, beta, cat_target, num_target, out);
}